// Round 3
// baseline (281.415 us; speedup 1.0000x reference)
//
#include <hip/hip_runtime.h>
#include <math.h>

// Problem constants (B=64, P=2, H=512, W=512)
#define HH 512
#define WW 512
#define BP 128                  // B*P pairs
#define PLANE (HH * WW)         // 262144 elems per (b,p) plane
#define SEG2 32                 // segments per pair
#define SEG_FLOATS 8192         // floats per segment (32 KB)
#define NPART2 (BP * SEG2)      // 4096 partial records per quantity
#define CHUNK_F 1024            // floats per pipeline chunk (4 KB)
#define NCHUNK 8                // chunks per segment

// ws float layout: [0,4096) sum, [4096,8192) sumx, [8192,12288) sumy,
// [12288,16384) maxval ; ints at float offset [16384,20480) maxidx. 80 KiB.

// R7: persistent pipelined streamer. R0-R6 were all one-shot-drain kernels
// (burst loads -> full vmcnt(0) drain -> compute -> exit); all pinned at
// 2.7 TB/s delivered / ~99 us regardless of issue mechanism. This version is
// shaped like the 6.3 TB/s copy ubench: each wave owns one 32 KB segment and
// streams it through a 2x4KB LDS double buffer with counted vmcnt(4) waits —
// 8 KB permanently in flight per wave, never draining to 0 until the last
// chunk. No __syncthreads anywhere (waves touch only their own LDS quarter).
// 5 blocks/CU resident -> ~160 KB in flight per CU (~10x Little's law need).
__device__ __forceinline__ void gload_lds16(const float* g, float* l)
{
    __builtin_amdgcn_global_load_lds(
        (const __attribute__((address_space(1))) void*)g,
        (__attribute__((address_space(3))) void*)l, 16, 0, 0);
}

// Issue one 4 KB chunk: 4 DMA loads of 1 KB (64 lanes x 16 B).
// LDS dest wave-uniform + lane*16 (HW requirement); global src per-lane.
__device__ __forceinline__ void issue_chunk(const float* gsrc, float* ldst,
                                            int lane)
{
#pragma unroll
    for (int ld = 0; ld < 4; ++ld)
        gload_lds16(gsrc + ld * 256 + lane * 4, ldst + ld * 256);
}

__global__ __launch_bounds__(256) void dsnt_partial(
    const float* __restrict__ inp, const float* __restrict__ tgt,
    float* __restrict__ wsf, int* __restrict__ wsi)
{
    const int tid  = threadIdx.x;
    const int lane = tid & 63, wid = tid >> 6;
    const float inv = 1.0f / 512.0f;

    __shared__ float lds[4][2][CHUNK_F];   // per-wave double buffer, 32 KB

    const int  g     = blockIdx.x * 4 + wid;   // segment id 0..8191
    const bool is_sm = (g < NPART2);
    const int  b2    = is_sm ? g : g - NPART2;
    const int  pair  = b2 >> 5;
    const int  seg   = b2 & 31;
    const float* __restrict__ gbase =
        (is_sm ? inp : tgt) + (size_t)pair * PLANE + seg * SEG_FLOATS;
    const int segbase = seg * SEG_FLOATS;

    float* const bufA = &lds[wid][0][0];
    float* const bufB = &lds[wid][1][0];

    // Prologue: fill both buffers' requests (8 loads in flight).
    issue_chunk(gbase + 0 * CHUNK_F, bufA, lane);
    issue_chunk(gbase + 1 * CHUNK_F, bufB, lane);

    if (is_sm) {
        // ---- softmax partial sums ----
        float s = 0.0f, sx = 0.0f, sy = 0.0f;
#pragma unroll
        for (int c = 0; c < NCHUNK; ++c) {
            float* const buf = (c & 1) ? bufB : bufA;
            // Counted wait: chunk c landed, next chunk's 4 loads still flying.
            if (c < NCHUNK - 1)
                asm volatile("s_waitcnt vmcnt(4)" ::: "memory");
            else
                asm volatile("s_waitcnt vmcnt(0)" ::: "memory");
            const float4* const lp = (const float4*)buf;
#pragma unroll
            for (int i = 0; i < 4; ++i) {
                const float4 v = lp[i * 64 + lane];
                const int f = segbase + c * CHUNK_F + (i * 64 + lane) * 4;
                const float yw  = (float)((f >> 9) + 1) * inv;
                const float xw0 = (float)((f & 511) + 1) * inv;
                const float e0 = __expf(v.x);
                const float e1 = __expf(v.y);
                const float e2 = __expf(v.z);
                const float e3 = __expf(v.w);
                const float es = e0 + e1 + e2 + e3;
                s  += es;
                sx += es * xw0 + inv * (e1 + 2.0f * e2 + 3.0f * e3);
                sy += es * yw;
            }
            if (c + 2 < NCHUNK) {
                // All ds_reads of this buffer done before DMA overwrites it.
                asm volatile("s_waitcnt lgkmcnt(0)" ::: "memory");
                issue_chunk(gbase + (c + 2) * CHUNK_F, buf, lane);
            }
        }

#pragma unroll
        for (int off = 32; off > 0; off >>= 1) {
            s  += __shfl_down(s,  off, 64);
            sx += __shfl_down(sx, off, 64);
            sy += __shfl_down(sy, off, 64);
        }
        if (lane == 0) {
            wsf[g]              = s;
            wsf[NPART2 + g]     = sx;
            wsf[2 * NPART2 + g] = sy;
        }
    } else {
        // ---- argmax partial over target ----
        float mv = -1.0f;
        int   mi = 0;
#pragma unroll
        for (int c = 0; c < NCHUNK; ++c) {
            float* const buf = (c & 1) ? bufB : bufA;
            if (c < NCHUNK - 1)
                asm volatile("s_waitcnt vmcnt(4)" ::: "memory");
            else
                asm volatile("s_waitcnt vmcnt(0)" ::: "memory");
            const float4* const lp = (const float4*)buf;
#pragma unroll
            for (int i = 0; i < 4; ++i) {
                const float4 v = lp[i * 64 + lane];
                const int f = segbase + c * CHUNK_F + (i * 64 + lane) * 4;
                if (v.x > mv) { mv = v.x; mi = f; }
                if (v.y > mv) { mv = v.y; mi = f + 1; }
                if (v.z > mv) { mv = v.z; mi = f + 2; }
                if (v.w > mv) { mv = v.w; mi = f + 3; }
            }
            if (c + 2 < NCHUNK) {
                asm volatile("s_waitcnt lgkmcnt(0)" ::: "memory");
                issue_chunk(gbase + (c + 2) * CHUNK_F, buf, lane);
            }
        }

#pragma unroll
        for (int off = 32; off > 0; off >>= 1) {
            const float ov = __shfl_down(mv, off, 64);
            const int   oi = __shfl_down(mi, off, 64);
            if (ov > mv || (ov == mv && oi < mi)) { mv = ov; mi = oi; }
        }
        if (lane == 0) {
            wsf[3 * NPART2 + b2] = mv;
            wsi[b2]              = mi;
        }
    }
}

__global__ __launch_bounds__(128) void dsnt_finalize(
    const float* __restrict__ wsf, const int* __restrict__ wsi,
    float* __restrict__ out)
{
    __shared__ float px[BP], py[BP], tx[BP], ty[BP];
    __shared__ float wsum[2];
    const int tid = threadIdx.x; // 0..127, one pair per thread

    {
        float s = 0.0f, sx = 0.0f, sy = 0.0f, mv = -1.0f;
        int mi = 0;
#pragma unroll
        for (int k = 0; k < SEG2; ++k) {
            const int i = tid * SEG2 + k;  // segs in ascending index order
            s  += wsf[i];
            sx += wsf[NPART2 + i];
            sy += wsf[2 * NPART2 + i];
            const float v = wsf[3 * NPART2 + i];
            const int  ii = wsi[i];
            if (v > mv || (v == mv && ii < mi)) { mv = v; mi = ii; }
        }
        px[tid] = sx / s;
        py[tid] = sy / s;
        tx[tid] = (float)((mi & 511) + 1) * (1.0f / 512.0f);
        ty[tid] = (float)((mi >> 9) + 1) * (1.0f / 512.0f);
    }
    __syncthreads();

    float term = 0.0f;
    if (tid < 64) {
        const int b = tid;
        const float px0 = px[2 * b], px1 = px[2 * b + 1];
        const float py0 = py[2 * b], py1 = py[2 * b + 1];
        const float tx0 = tx[2 * b], tx1 = tx[2 * b + 1];
        const float ty0 = ty[2 * b], ty1 = ty[2 * b + 1];

        const float ed0 = sqrtf((tx0 - px0) * (tx0 - px0) + (ty0 - py0) * (ty0 - py0));
        const float ed1 = sqrtf((tx1 - px1) * (tx1 - px1) + (ty1 - py1) * (ty1 - py1));

        const float pvx = px0 - px1, pvy = py0 - py1;
        const float tvx = tx0 - tx1, tvy = ty0 - ty1;
        const float pd = sqrtf(pvx * pvx + pvy * pvy);
        const float td = sqrtf(tvx * tvx + tvy * tvy);
        const float dot = pvx * tvx + pvy * tvy;
        const float cosd = 1.0f - cosf(dot / (pd * td));
        term = ed0 + ed1 + fabsf(pd - td) + cosd;
    }

#pragma unroll
    for (int off = 32; off > 0; off >>= 1)
        term += __shfl_down(term, off, 64);
    const int lane = tid & 63, wid = tid >> 6;
    if (lane == 0) wsum[wid] = term;
    __syncthreads();
    if (tid == 0) out[0] = (wsum[0] + wsum[1]) * (1.0f / 64.0f);
}

extern "C" void kernel_launch(void* const* d_in, const int* in_sizes, int n_in,
                              void* d_out, int out_size, void* d_ws, size_t ws_size,
                              hipStream_t stream)
{
    const float* inp = (const float*)d_in[0];
    const float* tgt = (const float*)d_in[1];
    float* out = (float*)d_out;
    float* wsf = (float*)d_ws;
    int*   wsi = (int*)((float*)d_ws + 4 * NPART2);

    dsnt_partial<<<2048, 256, 0, stream>>>(inp, tgt, wsf, wsi);
    dsnt_finalize<<<1, 128, 0, stream>>>(wsf, wsi, out);
}

// Round 4
// 258.683 us; speedup vs baseline: 1.0879x; 1.0879x over previous
//
#include <hip/hip_runtime.h>
#include <math.h>

// Problem constants (B=64, P=2, H=512, W=512)
#define HH 512
#define WW 512
#define BP 128                  // B*P pairs
#define PLANE (HH * WW)         // 262144 elems per (b,p) plane
#define SEG2 32                 // segments per pair
#define SEG_FLOATS 8192         // floats per segment (32 KB)
#define NPART2 (BP * SEG2)      // 4096 partial records per quantity

// ws float layout: [0,4096) sum, [4096,8192) sumx, [8192,12288) sumy,
// [12288,16384) maxval ; ints at float offset [16384,20480) maxidx. 80 KiB.

// R8: non-temporal streaming. R0 (reg burst), R6 (DMA one-shot), R7
// (persistent counted-vmcnt pipeline) all pin at 98.5-101 us / 2.7 TB/s
// delivered despite 10x differences in in-flight bytes and occupancy ->
// downstream service limit, not request supply. Working set (256 MiB)
// exactly equals Infinity Cache capacity: streaming-thrash regime, and
// exactly half the traffic (134 MB) comes from HBM each iteration. Theory:
// the IC allocate/hit path is the ~2.7 TB/s bottleneck. Fix under test:
// __builtin_nontemporal_load (nt flag) so the stream doesn't allocate in
// IC; misses then stream at HBM rate (~6.3 TB/s => ~45 us).
typedef float f4 __attribute__((ext_vector_type(4)));

__global__ __launch_bounds__(256) void dsnt_partial(
    const float* __restrict__ inp, const float* __restrict__ tgt,
    float* __restrict__ wsf, int* __restrict__ wsi)
{
    const int tid  = threadIdx.x;
    const int blk  = blockIdx.x;
    const int lane = tid & 63, wid = tid >> 6;
    const float inv = 1.0f / 512.0f;

    __shared__ float rs[4], rsx[4], rsy[4], rmv[4];
    __shared__ int   rmi[4];

    const bool is_sm = (blk < NPART2);
    const int  b2    = is_sm ? blk : blk - NPART2;
    const int  pair  = b2 >> 5;
    const int  seg   = b2 & 31;
    const f4* __restrict__ gp =
        (const f4*)((is_sm ? inp : tgt) + (size_t)pair * PLANE + seg * SEG_FLOATS);
    const int segbase = seg * SEG_FLOATS;

    if (is_sm) {
        // ---- softmax partial sums, depth-2 nt pipeline ----
        float s = 0.0f, sx = 0.0f, sy = 0.0f;
        f4 cur = __builtin_nontemporal_load(gp + tid);
#pragma unroll
        for (int j = 0; j < 8; ++j) {
            f4 nxt;
            if (j < 7) nxt = __builtin_nontemporal_load(gp + (j + 1) * 256 + tid);
            const int f = segbase + (j * 256 + tid) * 4;  // %4==0, no row cross
            const float yw  = (float)((f >> 9) + 1) * inv;
            const float xw0 = (float)((f & 511) + 1) * inv;
            const float e0 = __expf(cur.x);
            const float e1 = __expf(cur.y);
            const float e2 = __expf(cur.z);
            const float e3 = __expf(cur.w);
            const float es = e0 + e1 + e2 + e3;
            s  += es;
            sx += es * xw0 + inv * (e1 + 2.0f * e2 + 3.0f * e3);
            sy += es * yw;
            if (j < 7) cur = nxt;
        }

#pragma unroll
        for (int off = 32; off > 0; off >>= 1) {
            s  += __shfl_down(s,  off, 64);
            sx += __shfl_down(sx, off, 64);
            sy += __shfl_down(sy, off, 64);
        }
        if (lane == 0) { rs[wid] = s; rsx[wid] = sx; rsy[wid] = sy; }
        __syncthreads();
        if (tid == 0) {
            float fs = rs[0], fsx = rsx[0], fsy = rsy[0];
#pragma unroll
            for (int k = 1; k < 4; ++k) { fs += rs[k]; fsx += rsx[k]; fsy += rsy[k]; }
            wsf[blk]              = fs;
            wsf[NPART2 + blk]     = fsx;
            wsf[2 * NPART2 + blk] = fsy;
        }
    } else {
        // ---- argmax partial over target, depth-2 nt pipeline ----
        float mv = -1.0f;
        int   mi = 0;
        f4 cur = __builtin_nontemporal_load(gp + tid);
#pragma unroll
        for (int j = 0; j < 8; ++j) {
            f4 nxt;
            if (j < 7) nxt = __builtin_nontemporal_load(gp + (j + 1) * 256 + tid);
            const int f = segbase + (j * 256 + tid) * 4;
            if (cur.x > mv) { mv = cur.x; mi = f; }
            if (cur.y > mv) { mv = cur.y; mi = f + 1; }
            if (cur.z > mv) { mv = cur.z; mi = f + 2; }
            if (cur.w > mv) { mv = cur.w; mi = f + 3; }
            if (j < 7) cur = nxt;
        }

#pragma unroll
        for (int off = 32; off > 0; off >>= 1) {
            const float ov = __shfl_down(mv, off, 64);
            const int   oi = __shfl_down(mi, off, 64);
            if (ov > mv || (ov == mv && oi < mi)) { mv = ov; mi = oi; }
        }
        if (lane == 0) { rmv[wid] = mv; rmi[wid] = mi; }
        __syncthreads();
        if (tid == 0) {
            float fmv = rmv[0];
            int   fmi = rmi[0];
#pragma unroll
            for (int k = 1; k < 4; ++k)
                if (rmv[k] > fmv || (rmv[k] == fmv && rmi[k] < fmi)) { fmv = rmv[k]; fmi = rmi[k]; }
            wsf[3 * NPART2 + b2] = fmv;
            wsi[b2]              = fmi;
        }
    }
}

__global__ __launch_bounds__(128) void dsnt_finalize(
    const float* __restrict__ wsf, const int* __restrict__ wsi,
    float* __restrict__ out)
{
    __shared__ float px[BP], py[BP], tx[BP], ty[BP];
    __shared__ float wsum[2];
    const int tid = threadIdx.x; // 0..127, one pair per thread

    {
        float s = 0.0f, sx = 0.0f, sy = 0.0f, mv = -1.0f;
        int mi = 0;
#pragma unroll
        for (int k = 0; k < SEG2; ++k) {
            const int i = tid * SEG2 + k;  // segs in ascending index order
            s  += wsf[i];
            sx += wsf[NPART2 + i];
            sy += wsf[2 * NPART2 + i];
            const float v = wsf[3 * NPART2 + i];
            const int  ii = wsi[i];
            if (v > mv || (v == mv && ii < mi)) { mv = v; mi = ii; }
        }
        px[tid] = sx / s;
        py[tid] = sy / s;
        tx[tid] = (float)((mi & 511) + 1) * (1.0f / 512.0f);
        ty[tid] = (float)((mi >> 9) + 1) * (1.0f / 512.0f);
    }
    __syncthreads();

    float term = 0.0f;
    if (tid < 64) {
        const int b = tid;
        const float px0 = px[2 * b], px1 = px[2 * b + 1];
        const float py0 = py[2 * b], py1 = py[2 * b + 1];
        const float tx0 = tx[2 * b], tx1 = tx[2 * b + 1];
        const float ty0 = ty[2 * b], ty1 = ty[2 * b + 1];

        const float ed0 = sqrtf((tx0 - px0) * (tx0 - px0) + (ty0 - py0) * (ty0 - py0));
        const float ed1 = sqrtf((tx1 - px1) * (tx1 - px1) + (ty1 - py1) * (ty1 - py1));

        const float pvx = px0 - px1, pvy = py0 - py1;
        const float tvx = tx0 - tx1, tvy = ty0 - ty1;
        const float pd = sqrtf(pvx * pvx + pvy * pvy);
        const float td = sqrtf(tvx * tvx + tvy * tvy);
        const float dot = pvx * tvx + pvy * tvy;
        const float cosd = 1.0f - cosf(dot / (pd * td));
        term = ed0 + ed1 + fabsf(pd - td) + cosd;
    }

#pragma unroll
    for (int off = 32; off > 0; off >>= 1)
        term += __shfl_down(term, off, 64);
    const int lane = tid & 63, wid = tid >> 6;
    if (lane == 0) wsum[wid] = term;
    __syncthreads();
    if (tid == 0) out[0] = (wsum[0] + wsum[1]) * (1.0f / 64.0f);
}

extern "C" void kernel_launch(void* const* d_in, const int* in_sizes, int n_in,
                              void* d_out, int out_size, void* d_ws, size_t ws_size,
                              hipStream_t stream)
{
    const float* inp = (const float*)d_in[0];
    const float* tgt = (const float*)d_in[1];
    float* out = (float*)d_out;
    float* wsf = (float*)d_ws;
    int*   wsi = (int*)((float*)d_ws + 4 * NPART2);

    dsnt_partial<<<2 * NPART2, 256, 0, stream>>>(inp, tgt, wsf, wsi);
    dsnt_finalize<<<1, 128, 0, stream>>>(wsf, wsi, out);
}